// Round 2
// 421.474 us; speedup vs baseline: 1.0054x; 1.0054x over previous
//
#include <hip/hip_runtime.h>

typedef __bf16 bf16_t;
typedef bf16_t bf16x8 __attribute__((ext_vector_type(8)));
typedef float f32x4 __attribute__((ext_vector_type(4)));

#define HIDDEN 2048
#define SEQ 2048
#define BATCH 2
#define NHEADS 16
#define HDIM 128
#define MTOT (BATCH*SEQ)
#define SCALE 0.088388347648318447f
#define C1EXP2 0.12753102158508967f   /* SCALE * log2(e) */
#define LOG2E  1.4426950408889634f

// device exp2 without touching libm names (math.h macro collision on this toolchain)
__device__ __forceinline__ float dev_exp2(float x) { return __builtin_amdgcn_exp2f(x); }

// ---- async global->LDS (wave-uniform LDS base + lane*16, per m97) ----
typedef __attribute__((address_space(1))) const void gvoid_t;
typedef __attribute__((address_space(3))) void svoid_t;
__device__ __forceinline__ void async_copy16(const bf16_t* g, bf16_t* l) {
  __builtin_amdgcn_global_load_lds((gvoid_t*)g, (svoid_t*)l, 16, 0, 0);
}

// ---- fused fp32 -> bf16 cast for x + 4 weights (one dispatch) ----
__global__ void cvt_all(const float* __restrict__ x,  const float* __restrict__ wq,
                        const float* __restrict__ wk, const float* __restrict__ wv,
                        const float* __restrict__ wo,
                        bf16_t* __restrict__ xb, bf16_t* __restrict__ wqkb,
                        bf16_t* __restrict__ wvb, bf16_t* __restrict__ wob) {
  const size_t HH = (size_t)HIDDEN * HIDDEN;
  const float* src; bf16_t* dst;
  switch (blockIdx.y) {
    case 0:  src = x;        dst = xb;        break;
    case 1:  src = x + HH;   dst = xb + HH;   break;
    case 2:  src = wq;       dst = wqkb;      break;
    case 3:  src = wk;       dst = wqkb + HH; break;
    case 4:  src = wv;       dst = wvb;       break;
    default: src = wo;       dst = wob;       break;
  }
  int i = blockIdx.x * 256 + threadIdx.x;     // HH/4 float4s per region
  float4 v = reinterpret_cast<const float4*>(src)[i];
  union { bf16_t h[4]; uint2 u; } t;
  t.h[0] = (bf16_t)v.x; t.h[1] = (bf16_t)v.y; t.h[2] = (bf16_t)v.z; t.h[3] = (bf16_t)v.w;
  reinterpret_cast<uint2*>(dst)[i] = t.u;
}

__global__ void pack_bias2(const float* __restrict__ a, const float* __restrict__ b2,
                           float* __restrict__ out) {
  int i = blockIdx.x * 256 + threadIdx.x;      // 0..4095
  out[i] = (i < HIDDEN) ? a[i] : b2[i - HIDDEN];
}

// ---- GEMM: Y[i][j] = sum_k A[i][k]*Bt[j][k] + bias  (both operands K-major) ----
// 128x128 tile, BK=32, 4 waves in 2x2, 16x16x32 bf16 MFMA. m97 structure.
template<bool OUT_BF16, bool ROW_BIAS>
__global__ __launch_bounds__(256, 3)
void gemm_bt(const bf16_t* __restrict__ A, const bf16_t* __restrict__ Bt,
             const float* __restrict__ bias, void* __restrict__ Yv,
             int M, int N, int K, int ldY) {
  __shared__ __align__(16) bf16_t As[128 * 32];
  __shared__ __align__(16) bf16_t Bs[128 * 32];
  const int tid  = threadIdx.x;
  const int lane = tid & 63;
  const int wv   = tid >> 6;
  const int wr   = wv >> 1, wc = wv & 1;
  const int lr   = lane & 15, quad = lane >> 4;
  const int n0   = blockIdx.x * 128;
  const int m0   = blockIdx.y * 128;

  f32x4 acc[4][4] = {};

  const int srow = wv * 16 + (lane >> 2);      // 0..63
  const int scol = (lane & 3) * 8;
  const bf16_t* gA = A  + (size_t)(m0 + srow) * K + scol;
  const bf16_t* gB = Bt + (size_t)(n0 + srow) * K + scol;
  bf16_t* lA = &As[wv * 16 * 32];              // wave-uniform LDS base
  bf16_t* lB = &Bs[wv * 16 * 32];
  const size_t step64 = (size_t)64 * K;

  for (int kt = 0; kt < K; kt += 32) {
    __syncthreads();                           // prior ds_reads complete
    async_copy16(gA,          lA);
    async_copy16(gA + step64, lA + 64 * 32);
    async_copy16(gB,          lB);
    async_copy16(gB + step64, lB + 64 * 32);
    gA += 32; gB += 32;
    __syncthreads();                           // drains vmcnt -> tiles visible
    bf16x8 af[4], bfr[4];
#pragma unroll
    for (int mi = 0; mi < 4; ++mi)
      af[mi] = *(const bf16x8*)&As[(wr * 64 + mi * 16 + lr) * 32 + quad * 8];
#pragma unroll
    for (int ni = 0; ni < 4; ++ni)
      bfr[ni] = *(const bf16x8*)&Bs[(wc * 64 + ni * 16 + lr) * 32 + quad * 8];
#pragma unroll
    for (int mi = 0; mi < 4; ++mi)
#pragma unroll
      for (int ni = 0; ni < 4; ++ni)
        acc[mi][ni] = __builtin_amdgcn_mfma_f32_16x16x32_bf16(af[mi], bfr[ni], acc[mi][ni], 0, 0, 0);
  }

  float bcol[4];
  if (!ROW_BIAS) {
#pragma unroll
    for (int ni = 0; ni < 4; ++ni) bcol[ni] = bias[n0 + wc * 64 + ni * 16 + lr];
  }
#pragma unroll
  for (int mi = 0; mi < 4; ++mi) {
#pragma unroll
    for (int r = 0; r < 4; ++r) {
      int row = m0 + wr * 64 + mi * 16 + quad * 4 + r;
      float brow = ROW_BIAS ? bias[row] : 0.0f;
      size_t base = (size_t)row * ldY + n0 + wc * 64;
#pragma unroll
      for (int ni = 0; ni < 4; ++ni) {
        float y = acc[mi][ni][r] + (ROW_BIAS ? brow : bcol[ni]);
        int col = ni * 16 + lr;
        if (OUT_BF16) ((bf16_t*)Yv)[base + col] = (bf16_t)y;
        else          ((float*)Yv)[base + col]  = y;
      }
    }
  }
}

// ---- Flash attention v7: software-pipelined KV loop ----
// 4-wave blocks, BQ=128 (wave owns 32 q rows), BKV=64. K double-buffered,
// V single-buffered (its latency hides under QK^T+softmax). Mask pre-staged
// to LDS so the ONLY in-loop VMEM ops are the 8 staging global_load_lds per
// wave -> counted s_waitcnt vmcnt(8/4) are exact (HK derived-waits pattern).
// Raw s_barrier everywhere in the loop: __syncthreads() would emit
// s_waitcnt vmcnt(0) and drain the prefetch (the m97 ~20% stall).
// LDS = 32K (Ks dbuf) + 16K (Vs) + 16K (Ps) + 8K (mask) = 72 KB -> 2
// blocks/CU = 8 waves/CU, grid 512 = exactly 2 resident rounds.
// Schedule per tile kt (per wave, vmcnt in parens = outstanding after):
//   lgkmcnt(0); s_barrier          ; prev iter done reading Vs/Ps/Ks[cur^1]
//   issue V(kt) -> Vs        (K(kt)4 + V4 = 8)
//   issue K(kt+1) -> Ks[^1]  (12)
//   s_waitcnt vmcnt(8)             ; K(kt) landed (oldest 4 retired)
//   s_barrier                      ; K(kt) visible to all waves
//   QK^T + softmax -> Ps           ; covers V(kt) latency
//   s_waitcnt vmcnt(4)             ; V(kt) landed, K(kt+1) still in flight
//   s_barrier                      ; V visible
//   PV
#define BQ 128
#define BKV 64
#define LDQK 4096

__global__ __launch_bounds__(256, 2)
void attn_kernel(const bf16_t* __restrict__ QK, const bf16_t* __restrict__ Vt,
                 const float* __restrict__ mask, bf16_t* __restrict__ O) {
  __shared__ __align__(16) bf16_t Ks[2][BKV * 128];  // 2 x 16 KB, swizzle key row&15
  __shared__ __align__(16) bf16_t Vs[HDIM * BKV];    // 16 KB, swizzle key d&7
  __shared__ __align__(16) bf16_t Ps[BQ * BKV];      // 16 KB, swizzle key row&7
  __shared__ __align__(16) float  Msk[SEQ];          // 8 KB, pre-scaled by log2e

  const int tid  = threadIdx.x;
  const int lane = tid & 63;
  const int wv   = tid >> 6;                       // wave owns q rows [wv*32, wv*32+32)
  const int lr   = lane & 15, quad = lane >> 4;
  const int q0   = blockIdx.x * BQ;
  const int bh   = blockIdx.y;
  const int b    = bh >> 4, h = bh & 15;

  const bf16_t* Qg = QK + (size_t)(b * SEQ + q0) * LDQK + h * HDIM;
  const bf16_t* Kg = QK + (size_t)(b * SEQ) * LDQK + HIDDEN + h * HDIM;
  const bf16_t* Vg = Vt + (size_t)(h * HDIM) * MTOT + b * SEQ;
  const float*  mb = mask + b * SEQ;

  // Q fragments straight from global (one-time; L2/L3-served). 32 VGPRs.
  bf16x8 qf[2][4];
#pragma unroll
  for (int mi = 0; mi < 2; ++mi)
#pragma unroll
    for (int dk = 0; dk < 4; ++dk)
      qf[mi][dk] = *(const bf16x8*)(Qg + (size_t)(wv * 32 + mi * 16 + lr) * LDQK + dk * 32 + quad * 8);

  // mask -> LDS once, pre-scaled (keeps the main loop free of compiler VMEM)
  for (int i = tid; i < SEQ / 4; i += 256) {
    float4 mv = reinterpret_cast<const float4*>(mb)[i];
    Msk[i * 4 + 0] = mv.x * LOG2E;
    Msk[i * 4 + 1] = mv.y * LOG2E;
    Msk[i * 4 + 2] = mv.z * LOG2E;
    Msk[i * 4 + 3] = mv.w * LOG2E;
  }

  // staging: K tile 64x128 = 16 calls (4/wave); V tile 128x64 = 16 calls (4/wave)
  const int kcs = lane & 15;                       // K chunk (16B units)
  const int vcs = lane & 7;                        // V chunk
  const bf16_t* kgp[4]; const bf16_t* vgp[4];
  int lKo[4], lVo[4];
#pragma unroll
  for (int i = 0; i < 4; ++i) {
    int kr = wv * 16 + i * 4 + (lane >> 4);        // 0..63
    kgp[i] = Kg + (size_t)kr * LDQK + ((kcs ^ (kr & 15)) * 8);
    lKo[i] = (wv * 16 + i * 4) * 128;              // wave-uniform; HW adds lane*16B
    int vr = wv * 32 + i * 8 + (lane >> 3);        // 0..127
    vgp[i] = Vg + (size_t)vr * MTOT + ((vcs ^ (vr & 7)) * 8);
    lVo[i] = (wv * 32 + i * 8) * 64;
  }

  // drain Q/mask VMEM so in-loop vmcnt counts only staging ops
  asm volatile("s_waitcnt vmcnt(0)" ::: "memory");
#pragma unroll
  for (int i = 0; i < 4; ++i) async_copy16(kgp[i], &Ks[0][lKo[i]]);  // K(0) in flight
  asm volatile("s_waitcnt lgkmcnt(0)" ::: "memory");                 // Msk writes done
  __builtin_amdgcn_s_barrier();                                      // Msk visible

  float l_st[2][4] = {};
  f32x4 oacc[2][8] = {};

  for (int kt = 0; kt < SEQ; kt += BKV) {
    const int cur = (kt >> 6) & 1;
    const bf16_t* Kc = &Ks[cur][0];

    // all prior ds ops (incl. PV's Vs reads) retired before tiles are re-staged
    asm volatile("s_waitcnt lgkmcnt(0)" ::: "memory");
    __builtin_amdgcn_s_barrier();   // all waves done reading Vs/Ps/Ks[cur^1]
#pragma unroll
    for (int i = 0; i < 4; ++i) async_copy16(vgp[i] + kt, &Vs[lVo[i]]);
    if (kt + BKV < SEQ) {
#pragma unroll
      for (int i = 0; i < 4; ++i)
        async_copy16(kgp[i] + (size_t)(kt + BKV) * LDQK, &Ks[cur ^ 1][lKo[i]]);
      asm volatile("s_waitcnt vmcnt(8)" ::: "memory");  // K(kt) landed
    } else {
      asm volatile("s_waitcnt vmcnt(4)" ::: "memory");  // K(kt) landed
    }
    __builtin_amdgcn_s_barrier();   // K(kt) visible to all waves
    __builtin_amdgcn_sched_barrier(0);

    float mk[4];
#pragma unroll
    for (int ni = 0; ni < 4; ++ni) mk[ni] = Msk[kt + ni * 16 + lr];

    // S = Q K^T  (per wave: [32 q][64 k])
    f32x4 sacc[2][4] = {};
#pragma unroll
    for (int dk = 0; dk < 4; ++dk) {
      bf16x8 kf[4];
#pragma unroll
      for (int ni = 0; ni < 4; ++ni)
        kf[ni] = *(const bf16x8*)&Kc[(ni * 16 + lr) * 128 + (((dk * 4 + quad) ^ lr) * 8)];
#pragma unroll
      for (int mi = 0; mi < 2; ++mi)
#pragma unroll
        for (int ni = 0; ni < 4; ++ni)
          sacc[mi][ni] = __builtin_amdgcn_mfma_f32_16x16x32_bf16(qf[mi][dk], kf[ni], sacc[mi][ni], 0, 0, 0);
    }

    // unnormalized P = exp2(S*C1 + mask*log2e); C-layout row = quad*4+r, col = lr
#pragma unroll
    for (int mi = 0; mi < 2; ++mi) {
#pragma unroll
      for (int r = 0; r < 4; ++r) {
        float p0 = dev_exp2(fmaf(sacc[mi][0][r], C1EXP2, mk[0]));
        float p1 = dev_exp2(fmaf(sacc[mi][1][r], C1EXP2, mk[1]));
        float p2 = dev_exp2(fmaf(sacc[mi][2][r], C1EXP2, mk[2]));
        float p3 = dev_exp2(fmaf(sacc[mi][3][r], C1EXP2, mk[3]));
        int pr = wv * 32 + mi * 16 + quad * 4 + r;
        int key = pr & 7;
        Ps[pr * BKV + (((0 + (lr >> 3)) ^ key) * 8) + (lr & 7)] = (bf16_t)p0;
        Ps[pr * BKV + (((2 + (lr >> 3)) ^ key) * 8) + (lr & 7)] = (bf16_t)p1;
        Ps[pr * BKV + (((4 + (lr >> 3)) ^ key) * 8) + (lr & 7)] = (bf16_t)p2;
        Ps[pr * BKV + (((6 + (lr >> 3)) ^ key) * 8) + (lr & 7)] = (bf16_t)p3;
        l_st[mi][r] += (p0 + p1) + (p2 + p3);
      }
    }

    if (kt + BKV < SEQ) {
      asm volatile("s_waitcnt vmcnt(4)" ::: "memory");  // V(kt) landed, K(kt+1) in flight
    } else {
      asm volatile("s_waitcnt vmcnt(0)" ::: "memory");  // final drain
    }
    __builtin_amdgcn_s_barrier();   // V(kt) visible (Ps is wave-private)
    __builtin_amdgcn_sched_barrier(0);

    // O += P V   (per wave: [32 q][128 d])
#pragma unroll
    for (int ki = 0; ki < 2; ++ki) {
      bf16x8 pf[2];
#pragma unroll
      for (int mi = 0; mi < 2; ++mi)
        pf[mi] = *(const bf16x8*)&Ps[(wv * 32 + mi * 16 + lr) * BKV + (((ki * 4 + quad) ^ (lr & 7)) * 8)];
#pragma unroll
      for (int di = 0; di < 8; ++di) {
        bf16x8 vf = *(const bf16x8*)&Vs[(di * 16 + lr) * BKV + (((ki * 4 + quad) ^ (lr & 7)) * 8)];
#pragma unroll
        for (int mi = 0; mi < 2; ++mi)
          oacc[mi][di] = __builtin_amdgcn_mfma_f32_16x16x32_bf16(pf[mi], vf, oacc[mi][di], 0, 0, 0);
      }
    }
  }

  // epilogue: reduce l across the 16 lr-lanes, O /= l, write ctx bf16
  bf16_t* Ob = O + (size_t)(b * SEQ + q0) * HIDDEN + h * HDIM;
#pragma unroll
  for (int mi = 0; mi < 2; ++mi) {
#pragma unroll
    for (int r = 0; r < 4; ++r) {
      float s = l_st[mi][r];
      s += __shfl_xor(s, 1);
      s += __shfl_xor(s, 2);
      s += __shfl_xor(s, 4);
      s += __shfl_xor(s, 8);
      float inv = 1.0f / s;
      size_t rowoff = (size_t)(wv * 32 + mi * 16 + quad * 4 + r) * HIDDEN;
#pragma unroll
      for (int di = 0; di < 8; ++di)
        Ob[rowoff + di * 16 + lr] = (bf16_t)(oacc[mi][di][r] * inv);
    }
  }
}

extern "C" void kernel_launch(void* const* d_in, const int* in_sizes, int n_in,
                              void* d_out, int out_size, void* d_ws, size_t ws_size,
                              hipStream_t stream) {
  const float* x   = (const float*)d_in[0];
  const float* msk = (const float*)d_in[1];
  const float* Wq  = (const float*)d_in[2];
  const float* bq  = (const float*)d_in[3];
  const float* Wk  = (const float*)d_in[4];
  const float* bk  = (const float*)d_in[5];
  const float* Wv  = (const float*)d_in[6];
  const float* bv  = (const float*)d_in[7];
  const float* Wo  = (const float*)d_in[8];
  const float* bo  = (const float*)d_in[9];
  float* out = (float*)d_out;

  // workspace layout (bf16 elems), ~101 MB total
  bf16_t* Xb   = (bf16_t*)d_ws;
  bf16_t* Wqkb = Xb   + (size_t)MTOT * HIDDEN;            // Wq|Wk stacked [4096][2048]
  bf16_t* Wvb  = Wqkb + (size_t)2 * HIDDEN * HIDDEN;
  bf16_t* Wob  = Wvb  + (size_t)HIDDEN * HIDDEN;
  bf16_t* QKo  = Wob  + (size_t)HIDDEN * HIDDEN;          // [4096][4096]
  bf16_t* Vto  = QKo  + (size_t)MTOT * 2 * HIDDEN;        // [2048][4096]
  float*  bqk  = (float*)(Vto + (size_t)HIDDEN * MTOT);   // [4096] fp32
  bf16_t* Cb   = Xb;  // ctx aliases Xb (Xb dead after Vt GEMM)

  // fused casts: 6 regions x (HH/4 float4 / 256) blocks
  cvt_all<<<dim3(HIDDEN * HIDDEN / 4 / 256, 6), 256, 0, stream>>>(
      x, Wq, Wk, Wv, Wo, Xb, Wqkb, Wvb, Wob);
  pack_bias2<<<2 * HIDDEN / 256, 256, 0, stream>>>(bq, bk, bqk);

  // QK projection: [4096,2048] x [4096,2048]^T -> [4096][4096]
  gemm_bt<true, false><<<dim3(32, 32), 256, 0, stream>>>(Xb, Wqkb, bqk, QKo,
                                                         MTOT, 2 * HIDDEN, HIDDEN, 2 * HIDDEN);
  // V^T projection (operands swapped): [2048,2048] x [4096,2048]^T -> [2048][4096], row bias
  gemm_bt<true, true><<<dim3(32, 16), 256, 0, stream>>>(Wvb, Xb, bv, Vto,
                                                        HIDDEN, MTOT, HIDDEN, MTOT);
  // attention -> ctx bf16 [4096][2048]  (256-thread blocks, pipelined, 2 blocks/CU)
  attn_kernel<<<dim3(SEQ / BQ, BATCH * NHEADS), 256, 0, stream>>>(QKo, Vto, msk, Cb);
  // output projection -> fp32 out
  gemm_bt<false, false><<<dim3(16, 32), 256, 0, stream>>>(Cb, Wob, bo, out,
                                                          MTOT, HIDDEN, HIDDEN, HIDDEN);
}

// Round 3
// 414.638 us; speedup vs baseline: 1.0220x; 1.0165x over previous
//
#include <hip/hip_runtime.h>

typedef __bf16 bf16_t;
typedef bf16_t bf16x8 __attribute__((ext_vector_type(8)));
typedef float f32x4 __attribute__((ext_vector_type(4)));

#define HIDDEN 2048
#define SEQ 2048
#define BATCH 2
#define NHEADS 16
#define HDIM 128
#define MTOT (BATCH*SEQ)
#define SCALE 0.088388347648318447f
#define C1EXP2 0.12753102158508967f   /* SCALE * log2(e) */
#define LOG2E  1.4426950408889634f

// device exp2 without touching libm names (math.h macro collision on this toolchain)
__device__ __forceinline__ float dev_exp2(float x) { return __builtin_amdgcn_exp2f(x); }

// ---- async global->LDS (wave-uniform LDS base + lane*16, per m97) ----
typedef __attribute__((address_space(1))) const void gvoid_t;
typedef __attribute__((address_space(3))) void svoid_t;
__device__ __forceinline__ void async_copy16(const bf16_t* g, bf16_t* l) {
  __builtin_amdgcn_global_load_lds((gvoid_t*)g, (svoid_t*)l, 16, 0, 0);
}

// ---- fused fp32 -> bf16 cast for x + 4 weights (one dispatch) ----
__global__ void cvt_all(const float* __restrict__ x,  const float* __restrict__ wq,
                        const float* __restrict__ wk, const float* __restrict__ wv,
                        const float* __restrict__ wo,
                        bf16_t* __restrict__ xb, bf16_t* __restrict__ wqkb,
                        bf16_t* __restrict__ wvb, bf16_t* __restrict__ wob) {
  const size_t HH = (size_t)HIDDEN * HIDDEN;
  const float* src; bf16_t* dst;
  switch (blockIdx.y) {
    case 0:  src = x;        dst = xb;        break;
    case 1:  src = x + HH;   dst = xb + HH;   break;
    case 2:  src = wq;       dst = wqkb;      break;
    case 3:  src = wk;       dst = wqkb + HH; break;
    case 4:  src = wv;       dst = wvb;       break;
    default: src = wo;       dst = wob;       break;
  }
  int i = blockIdx.x * 256 + threadIdx.x;     // HH/4 float4s per region
  float4 v = reinterpret_cast<const float4*>(src)[i];
  union { bf16_t h[4]; uint2 u; } t;
  t.h[0] = (bf16_t)v.x; t.h[1] = (bf16_t)v.y; t.h[2] = (bf16_t)v.z; t.h[3] = (bf16_t)v.w;
  reinterpret_cast<uint2*>(dst)[i] = t.u;
}

__global__ void pack_bias2(const float* __restrict__ a, const float* __restrict__ b2,
                           float* __restrict__ out) {
  int i = blockIdx.x * 256 + threadIdx.x;      // 0..4095
  out[i] = (i < HIDDEN) ? a[i] : b2[i - HIDDEN];
}

// ---- GEMM: Y[i][j] = sum_k A[i][k]*Bt[j][k] + bias  (both operands K-major) ----
// 128x128 tile, BK=32, 4 waves in 2x2, 16x16x32 bf16 MFMA. m97 structure.
// Used for the two small GEMMs (Vt, out-proj: 512 WGs, 3 blocks/CU).
template<bool OUT_BF16, bool ROW_BIAS>
__global__ __launch_bounds__(256, 3)
void gemm_bt(const bf16_t* __restrict__ A, const bf16_t* __restrict__ Bt,
             const float* __restrict__ bias, void* __restrict__ Yv,
             int M, int N, int K, int ldY) {
  __shared__ __align__(16) bf16_t As[128 * 32];
  __shared__ __align__(16) bf16_t Bs[128 * 32];
  const int tid  = threadIdx.x;
  const int lane = tid & 63;
  const int wv   = tid >> 6;
  const int wr   = wv >> 1, wc = wv & 1;
  const int lr   = lane & 15, quad = lane >> 4;
  const int n0   = blockIdx.x * 128;
  const int m0   = blockIdx.y * 128;

  f32x4 acc[4][4] = {};

  const int srow = wv * 16 + (lane >> 2);      // 0..63
  const int scol = (lane & 3) * 8;
  const bf16_t* gA = A  + (size_t)(m0 + srow) * K + scol;
  const bf16_t* gB = Bt + (size_t)(n0 + srow) * K + scol;
  bf16_t* lA = &As[wv * 16 * 32];              // wave-uniform LDS base
  bf16_t* lB = &Bs[wv * 16 * 32];
  const size_t step64 = (size_t)64 * K;

  for (int kt = 0; kt < K; kt += 32) {
    __syncthreads();                           // prior ds_reads complete
    async_copy16(gA,          lA);
    async_copy16(gA + step64, lA + 64 * 32);
    async_copy16(gB,          lB);
    async_copy16(gB + step64, lB + 64 * 32);
    gA += 32; gB += 32;
    __syncthreads();                           // drains vmcnt -> tiles visible
    bf16x8 af[4], bfr[4];
#pragma unroll
    for (int mi = 0; mi < 4; ++mi)
      af[mi] = *(const bf16x8*)&As[(wr * 64 + mi * 16 + lr) * 32 + quad * 8];
#pragma unroll
    for (int ni = 0; ni < 4; ++ni)
      bfr[ni] = *(const bf16x8*)&Bs[(wc * 64 + ni * 16 + lr) * 32 + quad * 8];
#pragma unroll
    for (int mi = 0; mi < 4; ++mi)
#pragma unroll
      for (int ni = 0; ni < 4; ++ni)
        acc[mi][ni] = __builtin_amdgcn_mfma_f32_16x16x32_bf16(af[mi], bfr[ni], acc[mi][ni], 0, 0, 0);
  }

  float bcol[4];
  if (!ROW_BIAS) {
#pragma unroll
    for (int ni = 0; ni < 4; ++ni) bcol[ni] = bias[n0 + wc * 64 + ni * 16 + lr];
  }
#pragma unroll
  for (int mi = 0; mi < 4; ++mi) {
#pragma unroll
    for (int r = 0; r < 4; ++r) {
      int row = m0 + wr * 64 + mi * 16 + quad * 4 + r;
      float brow = ROW_BIAS ? bias[row] : 0.0f;
      size_t base = (size_t)row * ldY + n0 + wc * 64;
#pragma unroll
      for (int ni = 0; ni < 4; ++ni) {
        float y = acc[mi][ni][r] + (ROW_BIAS ? brow : bcol[ni]);
        int col = ni * 16 + lr;
        if (OUT_BF16) ((bf16_t*)Yv)[base + col] = (bf16_t)y;
        else          ((float*)Yv)[base + col]  = y;
      }
    }
  }
}

// ---- 256x256 8-phase GEMM for the QK projection (T2+T3+T4+T5 stack) ----
// Hardcoded: A[4096][2048] bf16, Bt[4096][2048] bf16, Y[4096][4096] bf16,
// col-bias fp32. 8 waves (2Mx4N), wave-tile 128x64, BK=64, 16x16x32 MFMA.
// LDS: 2 x (A 32K + B 32K) = 128 KB -> 1 block/CU, 256 WGs = 256 CUs.
// Per K-tile: 4 phases, each {ds_read subtile; lgkmcnt(0); setprio(1);
// 16 MFMA; setprio(0); s_barrier}. All 8 staging global_load_lds for tile
// t+1 burst at phase0 into buf^1 (that buffer's last read was one full
// group + barrier earlier -> WAR-safe); single vmcnt(0) at phase3 start
// (~3 phases of latency cover -> retires already-landed loads, never a
// post-issue drain). XOR-chunk swizzle (chunk ^ row&7) applied on BOTH
// sides: pre-swizzled per-lane global source (global_load_lds dest is
// linear lane*16) and swizzled ds_read address (rule #21 involution).
#define QKK 2048
#define STAGE256(buf, ktoff) do {                                              \
  _Pragma("unroll") for (int i_ = 0; i_ < 4; ++i_)                             \
    async_copy16(gA + (ktoff) + (size_t)(i_ * 8) * QKK,                        \
                 &As[buf][(wv * 32 + i_ * 8) * 64]);                           \
  _Pragma("unroll") for (int i_ = 0; i_ < 4; ++i_)                             \
    async_copy16(gB + (ktoff) + (size_t)(i_ * 8) * QKK,                        \
                 &Bs[buf][(wv * 32 + i_ * 8) * 64]);                           \
} while (0)
#define DS_A256(mh) do {                                                       \
  _Pragma("unroll") for (int mi_ = 0; mi_ < 4; ++mi_)                          \
    _Pragma("unroll") for (int kk_ = 0; kk_ < 2; ++kk_)                        \
      af[mi_][kk_] = *(const bf16x8*)&As[p][(wr * 128 + ((mh)*4 + mi_) * 16 + lr) * 64 \
                                           + (((kk_ * 4 + quad) ^ (lr & 7)) * 8)];     \
} while (0)
#define DS_B256(nh) do {                                                       \
  _Pragma("unroll") for (int ni_ = 0; ni_ < 2; ++ni_)                          \
    _Pragma("unroll") for (int kk_ = 0; kk_ < 2; ++kk_)                        \
      bfq[ni_][kk_] = *(const bf16x8*)&Bs[p][(wc * 64 + ((nh)*2 + ni_) * 16 + lr) * 64 \
                                            + (((kk_ * 4 + quad) ^ (lr & 7)) * 8)];    \
} while (0)
#define MFMA_Q256(mh, nh) do {                                                 \
  __builtin_amdgcn_s_setprio(1);                                               \
  _Pragma("unroll") for (int mi_ = 0; mi_ < 4; ++mi_)                          \
    _Pragma("unroll") for (int ni_ = 0; ni_ < 2; ++ni_) {                      \
      acc[(mh)*4 + mi_][(nh)*2 + ni_] = __builtin_amdgcn_mfma_f32_16x16x32_bf16( \
          af[mi_][0], bfq[ni_][0], acc[(mh)*4 + mi_][(nh)*2 + ni_], 0, 0, 0);  \
      acc[(mh)*4 + mi_][(nh)*2 + ni_] = __builtin_amdgcn_mfma_f32_16x16x32_bf16( \
          af[mi_][1], bfq[ni_][1], acc[(mh)*4 + mi_][(nh)*2 + ni_], 0, 0, 0);  \
    }                                                                          \
  __builtin_amdgcn_s_setprio(0);                                               \
} while (0)

__global__ __launch_bounds__(512, 2)
void gemm256_bt(const bf16_t* __restrict__ A, const bf16_t* __restrict__ Bt,
                const float* __restrict__ bias, bf16_t* __restrict__ Y) {
  __shared__ __align__(16) bf16_t As[2][256 * 64];   // 2 x 32 KB
  __shared__ __align__(16) bf16_t Bs[2][256 * 64];   // 2 x 32 KB
  const int tid  = threadIdx.x;
  const int lane = tid & 63;
  const int wv   = tid >> 6;                 // 0..7
  const int wr   = wv >> 2, wc = wv & 3;     // 2 x 4 wave grid
  const int lr   = lane & 15, quad = lane >> 4;

  // bijective XCD swizzle: 256 WGs, 8 XCDs, 32 contiguous per XCD
  const int wg  = blockIdx.x;
  const int swz = (wg & 7) * 32 + (wg >> 3);
  const int m0  = (swz >> 4) * 256;          // 16 M-blocks
  const int n0  = (swz & 15) * 256;          // 16 N-blocks

  f32x4 acc[8][4] = {};

  // staging sources: lane l writes LDS chunk (l&7) of row-octet-sub (l>>3);
  // source chunk = (l&7) ^ (l>>3) so LDS chunk c of row r holds global
  // chunk c ^ (r&7)  (r&7 == l>>3 since row bases are multiples of 8)
  const int sub = lane >> 3;
  const int ch  = (lane & 7) ^ sub;
  const bf16_t* gA = A  + (size_t)(m0 + wv * 32 + sub) * QKK + ch * 8;
  const bf16_t* gB = Bt + (size_t)(n0 + wv * 32 + sub) * QKK + ch * 8;

  // prologue: tile 0 -> buf 0, drain, barrier
  STAGE256(0, 0);
  asm volatile("s_waitcnt vmcnt(0)" ::: "memory");
  __builtin_amdgcn_s_barrier();

  bf16x8 af[4][2], bfq[2][2];

  for (int t = 0; t < QKK / 64; ++t) {
    const int p   = t & 1;
    const int ktb = t * 64;

    // phase 0: burst-stage tile t+1 into buf^1; compute quadrant (mlo,nlo)
    if (t + 1 < QKK / 64) STAGE256(p ^ 1, ktb + 64);
    DS_A256(0); DS_B256(0);
    asm volatile("s_waitcnt lgkmcnt(0)" ::: "memory");
    __builtin_amdgcn_sched_barrier(0);
    MFMA_Q256(0, 0);
    __builtin_amdgcn_s_barrier();

    // phase 1: (mlo,nhi) -- A frags reused
    DS_B256(1);
    asm volatile("s_waitcnt lgkmcnt(0)" ::: "memory");
    __builtin_amdgcn_sched_barrier(0);
    MFMA_Q256(0, 1);
    __builtin_amdgcn_s_barrier();

    // phase 2: (mhi,nhi) -- B frags reused
    DS_A256(1);
    asm volatile("s_waitcnt lgkmcnt(0)" ::: "memory");
    __builtin_amdgcn_sched_barrier(0);
    MFMA_Q256(1, 1);
    __builtin_amdgcn_s_barrier();

    // phase 3: (mhi,nlo) -- A reused, B re-read; tile t+1 landed (counted:
    // issued ~3 phases ago). Barrier gates next group's reads + restaging.
    DS_B256(0);
    asm volatile("s_waitcnt vmcnt(0) lgkmcnt(0)" ::: "memory");
    __builtin_amdgcn_sched_barrier(0);
    MFMA_Q256(1, 0);
    __builtin_amdgcn_s_barrier();
  }

  // epilogue: + col bias, cast bf16, store
  float bcol[4];
#pragma unroll
  for (int ni = 0; ni < 4; ++ni) bcol[ni] = bias[n0 + wc * 64 + ni * 16 + lr];
#pragma unroll
  for (int fm = 0; fm < 8; ++fm) {
#pragma unroll
    for (int r = 0; r < 4; ++r) {
      size_t row  = (size_t)(m0 + wr * 128 + fm * 16 + quad * 4 + r);
      size_t base = row * 4096 + n0 + wc * 64;
#pragma unroll
      for (int ni = 0; ni < 4; ++ni)
        Y[base + ni * 16 + lr] = (bf16_t)(acc[fm][ni][r] + bcol[ni]);
    }
  }
}

// ---- Flash attention v7: software-pipelined KV loop (unchanged from R2) ----
#define BQ 128
#define BKV 64
#define LDQK 4096

__global__ __launch_bounds__(256, 2)
void attn_kernel(const bf16_t* __restrict__ QK, const bf16_t* __restrict__ Vt,
                 const float* __restrict__ mask, bf16_t* __restrict__ O) {
  __shared__ __align__(16) bf16_t Ks[2][BKV * 128];  // 2 x 16 KB, swizzle key row&15
  __shared__ __align__(16) bf16_t Vs[HDIM * BKV];    // 16 KB, swizzle key d&7
  __shared__ __align__(16) bf16_t Ps[BQ * BKV];      // 16 KB, swizzle key row&7
  __shared__ __align__(16) float  Msk[SEQ];          // 8 KB, pre-scaled by log2e

  const int tid  = threadIdx.x;
  const int lane = tid & 63;
  const int wv   = tid >> 6;                       // wave owns q rows [wv*32, wv*32+32)
  const int lr   = lane & 15, quad = lane >> 4;
  const int q0   = blockIdx.x * BQ;
  const int bh   = blockIdx.y;
  const int b    = bh >> 4, h = bh & 15;

  const bf16_t* Qg = QK + (size_t)(b * SEQ + q0) * LDQK + h * HDIM;
  const bf16_t* Kg = QK + (size_t)(b * SEQ) * LDQK + HIDDEN + h * HDIM;
  const bf16_t* Vg = Vt + (size_t)(h * HDIM) * MTOT + b * SEQ;
  const float*  mb = mask + b * SEQ;

  // Q fragments straight from global (one-time; L2/L3-served). 32 VGPRs.
  bf16x8 qf[2][4];
#pragma unroll
  for (int mi = 0; mi < 2; ++mi)
#pragma unroll
    for (int dk = 0; dk < 4; ++dk)
      qf[mi][dk] = *(const bf16x8*)(Qg + (size_t)(wv * 32 + mi * 16 + lr) * LDQK + dk * 32 + quad * 8);

  // mask -> LDS once, pre-scaled (keeps the main loop free of compiler VMEM)
  for (int i = tid; i < SEQ / 4; i += 256) {
    float4 mv = reinterpret_cast<const float4*>(mb)[i];
    Msk[i * 4 + 0] = mv.x * LOG2E;
    Msk[i * 4 + 1] = mv.y * LOG2E;
    Msk[i * 4 + 2] = mv.z * LOG2E;
    Msk[i * 4 + 3] = mv.w * LOG2E;
  }

  // staging: K tile 64x128 = 16 calls (4/wave); V tile 128x64 = 16 calls (4/wave)
  const int kcs = lane & 15;                       // K chunk (16B units)
  const int vcs = lane & 7;                        // V chunk
  const bf16_t* kgp[4]; const bf16_t* vgp[4];
  int lKo[4], lVo[4];
#pragma unroll
  for (int i = 0; i < 4; ++i) {
    int kr = wv * 16 + i * 4 + (lane >> 4);        // 0..63
    kgp[i] = Kg + (size_t)kr * LDQK + ((kcs ^ (kr & 15)) * 8);
    lKo[i] = (wv * 16 + i * 4) * 128;              // wave-uniform; HW adds lane*16B
    int vr = wv * 32 + i * 8 + (lane >> 3);        // 0..127
    vgp[i] = Vg + (size_t)vr * MTOT + ((vcs ^ (vr & 7)) * 8);
    lVo[i] = (wv * 32 + i * 8) * 64;
  }

  // drain Q/mask VMEM so in-loop vmcnt counts only staging ops
  asm volatile("s_waitcnt vmcnt(0)" ::: "memory");
#pragma unroll
  for (int i = 0; i < 4; ++i) async_copy16(kgp[i], &Ks[0][lKo[i]]);  // K(0) in flight
  asm volatile("s_waitcnt lgkmcnt(0)" ::: "memory");                 // Msk writes done
  __builtin_amdgcn_s_barrier();                                      // Msk visible

  float l_st[2][4] = {};
  f32x4 oacc[2][8] = {};

  for (int kt = 0; kt < SEQ; kt += BKV) {
    const int cur = (kt >> 6) & 1;
    const bf16_t* Kc = &Ks[cur][0];

    // all prior ds ops (incl. PV's Vs reads) retired before tiles are re-staged
    asm volatile("s_waitcnt lgkmcnt(0)" ::: "memory");
    __builtin_amdgcn_s_barrier();   // all waves done reading Vs/Ps/Ks[cur^1]
#pragma unroll
    for (int i = 0; i < 4; ++i) async_copy16(vgp[i] + kt, &Vs[lVo[i]]);
    if (kt + BKV < SEQ) {
#pragma unroll
      for (int i = 0; i < 4; ++i)
        async_copy16(kgp[i] + (size_t)(kt + BKV) * LDQK, &Ks[cur ^ 1][lKo[i]]);
      asm volatile("s_waitcnt vmcnt(8)" ::: "memory");  // K(kt) landed
    } else {
      asm volatile("s_waitcnt vmcnt(4)" ::: "memory");  // K(kt) landed
    }
    __builtin_amdgcn_s_barrier();   // K(kt) visible to all waves
    __builtin_amdgcn_sched_barrier(0);

    float mk[4];
#pragma unroll
    for (int ni = 0; ni < 4; ++ni) mk[ni] = Msk[kt + ni * 16 + lr];

    // S = Q K^T  (per wave: [32 q][64 k])
    f32x4 sacc[2][4] = {};
#pragma unroll
    for (int dk = 0; dk < 4; ++dk) {
      bf16x8 kf[4];
#pragma unroll
      for (int ni = 0; ni < 4; ++ni)
        kf[ni] = *(const bf16x8*)&Kc[(ni * 16 + lr) * 128 + (((dk * 4 + quad) ^ lr) * 8)];
#pragma unroll
      for (int mi = 0; mi < 2; ++mi)
#pragma unroll
        for (int ni = 0; ni < 4; ++ni)
          sacc[mi][ni] = __builtin_amdgcn_mfma_f32_16x16x32_bf16(qf[mi][dk], kf[ni], sacc[mi][ni], 0, 0, 0);
    }

    // unnormalized P = exp2(S*C1 + mask*log2e); C-layout row = quad*4+r, col = lr
#pragma unroll
    for (int mi = 0; mi < 2; ++mi) {
#pragma unroll
      for (int r = 0; r < 4; ++r) {
        float p0 = dev_exp2(fmaf(sacc[mi][0][r], C1EXP2, mk[0]));
        float p1 = dev_exp2(fmaf(sacc[mi][1][r], C1EXP2, mk[1]));
        float p2 = dev_exp2(fmaf(sacc[mi][2][r], C1EXP2, mk[2]));
        float p3 = dev_exp2(fmaf(sacc[mi][3][r], C1EXP2, mk[3]));
        int pr = wv * 32 + mi * 16 + quad * 4 + r;
        int key = pr & 7;
        Ps[pr * BKV + (((0 + (lr >> 3)) ^ key) * 8) + (lr & 7)] = (bf16_t)p0;
        Ps[pr * BKV + (((2 + (lr >> 3)) ^ key) * 8) + (lr & 7)] = (bf16_t)p1;
        Ps[pr * BKV + (((4 + (lr >> 3)) ^ key) * 8) + (lr & 7)] = (bf16_t)p2;
        Ps[pr * BKV + (((6 + (lr >> 3)) ^ key) * 8) + (lr & 7)] = (bf16_t)p3;
        l_st[mi][r] += (p0 + p1) + (p2 + p3);
      }
    }

    if (kt + BKV < SEQ) {
      asm volatile("s_waitcnt vmcnt(4)" ::: "memory");  // V(kt) landed, K(kt+1) in flight
    } else {
      asm volatile("s_waitcnt vmcnt(0)" ::: "memory");  // final drain
    }
    __builtin_amdgcn_s_barrier();   // V(kt) visible (Ps is wave-private)
    __builtin_amdgcn_sched_barrier(0);

    // O += P V   (per wave: [32 q][128 d])
#pragma unroll
    for (int ki = 0; ki < 2; ++ki) {
      bf16x8 pf[2];
#pragma unroll
      for (int mi = 0; mi < 2; ++mi)
        pf[mi] = *(const bf16x8*)&Ps[(wv * 32 + mi * 16 + lr) * BKV + (((ki * 4 + quad) ^ (lr & 7)) * 8)];
#pragma unroll
      for (int di = 0; di < 8; ++di) {
        bf16x8 vf = *(const bf16x8*)&Vs[(di * 16 + lr) * BKV + (((ki * 4 + quad) ^ (lr & 7)) * 8)];
#pragma unroll
        for (int mi = 0; mi < 2; ++mi)
          oacc[mi][di] = __builtin_amdgcn_mfma_f32_16x16x32_bf16(pf[mi], vf, oacc[mi][di], 0, 0, 0);
      }
    }
  }

  // epilogue: reduce l across the 16 lr-lanes, O /= l, write ctx bf16
  bf16_t* Ob = O + (size_t)(b * SEQ + q0) * HIDDEN + h * HDIM;
#pragma unroll
  for (int mi = 0; mi < 2; ++mi) {
#pragma unroll
    for (int r = 0; r < 4; ++r) {
      float s = l_st[mi][r];
      s += __shfl_xor(s, 1);
      s += __shfl_xor(s, 2);
      s += __shfl_xor(s, 4);
      s += __shfl_xor(s, 8);
      float inv = 1.0f / s;
      size_t rowoff = (size_t)(wv * 32 + mi * 16 + quad * 4 + r) * HIDDEN;
#pragma unroll
      for (int di = 0; di < 8; ++di)
        Ob[rowoff + di * 16 + lr] = (bf16_t)(oacc[mi][di][r] * inv);
    }
  }
}

extern "C" void kernel_launch(void* const* d_in, const int* in_sizes, int n_in,
                              void* d_out, int out_size, void* d_ws, size_t ws_size,
                              hipStream_t stream) {
  const float* x   = (const float*)d_in[0];
  const float* msk = (const float*)d_in[1];
  const float* Wq  = (const float*)d_in[2];
  const float* bq  = (const float*)d_in[3];
  const float* Wk  = (const float*)d_in[4];
  const float* bk  = (const float*)d_in[5];
  const float* Wv  = (const float*)d_in[6];
  const float* bv  = (const float*)d_in[7];
  const float* Wo  = (const float*)d_in[8];
  const float* bo  = (const float*)d_in[9];
  float* out = (float*)d_out;

  // workspace layout (bf16 elems), ~101 MB total
  bf16_t* Xb   = (bf16_t*)d_ws;
  bf16_t* Wqkb = Xb   + (size_t)MTOT * HIDDEN;            // Wq|Wk stacked [4096][2048]
  bf16_t* Wvb  = Wqkb + (size_t)2 * HIDDEN * HIDDEN;
  bf16_t* Wob  = Wvb  + (size_t)HIDDEN * HIDDEN;
  bf16_t* QKo  = Wob  + (size_t)HIDDEN * HIDDEN;          // [4096][4096]
  bf16_t* Vto  = QKo  + (size_t)MTOT * 2 * HIDDEN;        // [2048][4096]
  float*  bqk  = (float*)(Vto + (size_t)HIDDEN * MTOT);   // [4096] fp32
  bf16_t* Cb   = Xb;  // ctx aliases Xb (Xb dead after Vt GEMM)

  // fused casts: 6 regions x (HH/4 float4 / 256) blocks
  cvt_all<<<dim3(HIDDEN * HIDDEN / 4 / 256, 6), 256, 0, stream>>>(
      x, Wq, Wk, Wv, Wo, Xb, Wqkb, Wvb, Wob);
  pack_bias2<<<2 * HIDDEN / 256, 256, 0, stream>>>(bq, bk, bqk);

  // QK projection: [4096,2048] x [4096,2048]^T -> [4096][4096]  (8-phase 256^2)
  gemm256_bt<<<256, 512, 0, stream>>>(Xb, Wqkb, bqk, QKo);
  // V^T projection (operands swapped): [2048,2048] x [4096,2048]^T -> [2048][4096], row bias
  gemm_bt<true, true><<<dim3(32, 16), 256, 0, stream>>>(Wvb, Xb, bv, Vto,
                                                        HIDDEN, MTOT, HIDDEN, MTOT);
  // attention -> ctx bf16 [4096][2048]  (256-thread blocks, pipelined, 2 blocks/CU)
  attn_kernel<<<dim3(SEQ / BQ, BATCH * NHEADS), 256, 0, stream>>>(QKo, Vto, msk, Cb);
  // output projection -> fp32 out
  gemm_bt<false, false><<<dim3(16, 32), 256, 0, stream>>>(Cb, Wob, bo, out,
                                                          MTOT, HIDDEN, HIDDEN, HIDDEN);
}

// Round 4
// 410.916 us; speedup vs baseline: 1.0313x; 1.0091x over previous
//
#include <hip/hip_runtime.h>

typedef __bf16 bf16_t;
typedef bf16_t bf16x8 __attribute__((ext_vector_type(8)));
typedef float f32x4 __attribute__((ext_vector_type(4)));

#define HIDDEN 2048
#define SEQ 2048
#define BATCH 2
#define NHEADS 16
#define HDIM 128
#define MTOT (BATCH*SEQ)
#define SCALE 0.088388347648318447f
#define C1EXP2 0.12753102158508967f   /* SCALE * log2(e) */
#define LOG2E  1.4426950408889634f

// device exp2 without touching libm names (math.h macro collision on this toolchain)
__device__ __forceinline__ float dev_exp2(float x) { return __builtin_amdgcn_exp2f(x); }

// ---- async global->LDS (wave-uniform LDS base + lane*16, per m97) ----
typedef __attribute__((address_space(1))) const void gvoid_t;
typedef __attribute__((address_space(3))) void svoid_t;
__device__ __forceinline__ void async_copy16(const bf16_t* g, bf16_t* l) {
  __builtin_amdgcn_global_load_lds((gvoid_t*)g, (svoid_t*)l, 16, 0, 0);
}

// ---- fused fp32 -> bf16 cast for x + 4 weights (one dispatch) ----
__global__ void cvt_all(const float* __restrict__ x,  const float* __restrict__ wq,
                        const float* __restrict__ wk, const float* __restrict__ wv,
                        const float* __restrict__ wo,
                        bf16_t* __restrict__ xb, bf16_t* __restrict__ wqkb,
                        bf16_t* __restrict__ wvb, bf16_t* __restrict__ wob) {
  const size_t HH = (size_t)HIDDEN * HIDDEN;
  const float* src; bf16_t* dst;
  switch (blockIdx.y) {
    case 0:  src = x;        dst = xb;        break;
    case 1:  src = x + HH;   dst = xb + HH;   break;
    case 2:  src = wq;       dst = wqkb;      break;
    case 3:  src = wk;       dst = wqkb + HH; break;
    case 4:  src = wv;       dst = wvb;       break;
    default: src = wo;       dst = wob;       break;
  }
  int i = blockIdx.x * 256 + threadIdx.x;     // HH/4 float4s per region
  float4 v = reinterpret_cast<const float4*>(src)[i];
  union { bf16_t h[4]; uint2 u; } t;
  t.h[0] = (bf16_t)v.x; t.h[1] = (bf16_t)v.y; t.h[2] = (bf16_t)v.z; t.h[3] = (bf16_t)v.w;
  reinterpret_cast<uint2*>(dst)[i] = t.u;
}

__global__ void pack_bias2(const float* __restrict__ a, const float* __restrict__ b2,
                           float* __restrict__ out) {
  int i = blockIdx.x * 256 + threadIdx.x;      // 0..4095
  out[i] = (i < HIDDEN) ? a[i] : b2[i - HIDDEN];
}

// ---- Pipelined GEMM: Y[i][j] = sum_k A[i][k]*Bt[j][k] + bias ----
// 128x128 tile, BK=32, 4 waves 2x2, 16x16x32 MFMA -- fragment layout and
// epilogue identical to the m97-style gemm_bt; ONLY the staging/sync is
// changed to T3/T4: triple-buffered LDS (3x16KB), depth-2 prefetch, counted
// s_waitcnt vmcnt(4) (full-iteration issue->wait distance), raw s_barrier
// (no __syncthreads vmcnt(0) drain). Ledger per wave (4 DMA calls/tile):
//   prologue: stage t0,t1 -> 8 outstanding
//   iter t:   vmcnt(4) [t landed, t+1 in flight]; lgkm(0); barrier;
//             stage t+2 into (t+2)%3 [freed: read in iter t-1, fenced by
//             this barrier]; ds_read tile t; lgkm(0); MFMA.
template<bool OUT_BF16, bool ROW_BIAS>
__global__ __launch_bounds__(256, 3)
void gemm_bt(const bf16_t* __restrict__ A, const bf16_t* __restrict__ Bt,
             const float* __restrict__ bias, void* __restrict__ Yv,
             int M, int N, int K, int ldY) {
  __shared__ __align__(16) bf16_t As[3][128 * 32];   // 24 KB
  __shared__ __align__(16) bf16_t Bs[3][128 * 32];   // 24 KB
  const int tid  = threadIdx.x;
  const int lane = tid & 63;
  const int wv   = tid >> 6;
  const int wr   = wv >> 1, wc = wv & 1;
  const int lr   = lane & 15, quad = lane >> 4;
  const int n0   = blockIdx.x * 128;
  const int m0   = blockIdx.y * 128;

  f32x4 acc[4][4] = {};

  const int srow = wv * 16 + (lane >> 2);      // 0..63
  const int scol = (lane & 3) * 8;
  const bf16_t* gA = A  + (size_t)(m0 + srow) * K + scol;
  const bf16_t* gB = Bt + (size_t)(n0 + srow) * K + scol;
  const int lbase = wv * 16 * 32;              // wave-uniform LDS base
  const size_t step64 = (size_t)64 * K;
  const int nt = K >> 5;

  // prologue: tiles 0 and 1 in flight (8 outstanding)
#pragma unroll
  for (int pt = 0; pt < 2; ++pt) {
    async_copy16(gA + pt * 32,          &As[pt][lbase]);
    async_copy16(gA + pt * 32 + step64, &As[pt][lbase + 64 * 32]);
    async_copy16(gB + pt * 32,          &Bs[pt][lbase]);
    async_copy16(gB + pt * 32 + step64, &Bs[pt][lbase + 64 * 32]);
  }

  int cur = 0;
  for (int t = 0; t < nt; ++t) {
    if (t + 1 < nt) { asm volatile("s_waitcnt vmcnt(4)" ::: "memory"); }
    else            { asm volatile("s_waitcnt vmcnt(0)" ::: "memory"); }
    asm volatile("s_waitcnt lgkmcnt(0)" ::: "memory");  // prev ds_reads retired
    __builtin_amdgcn_s_barrier();    // tile t visible; buf (t+2)%3 free
    __builtin_amdgcn_sched_barrier(0);

    if (t + 2 < nt) {
      const int stg = (cur >= 1) ? cur - 1 : 2;          // (t+2) % 3
      const int ko  = (t + 2) * 32;
      async_copy16(gA + ko,          &As[stg][lbase]);
      async_copy16(gA + ko + step64, &As[stg][lbase + 64 * 32]);
      async_copy16(gB + ko,          &Bs[stg][lbase]);
      async_copy16(gB + ko + step64, &Bs[stg][lbase + 64 * 32]);
    }

    bf16x8 af[4], bfr[4];
#pragma unroll
    for (int mi = 0; mi < 4; ++mi)
      af[mi] = *(const bf16x8*)&As[cur][(wr * 64 + mi * 16 + lr) * 32 + quad * 8];
#pragma unroll
    for (int ni = 0; ni < 4; ++ni)
      bfr[ni] = *(const bf16x8*)&Bs[cur][(wc * 64 + ni * 16 + lr) * 32 + quad * 8];
    asm volatile("s_waitcnt lgkmcnt(0)" ::: "memory");
    __builtin_amdgcn_sched_barrier(0);
    __builtin_amdgcn_s_setprio(1);
#pragma unroll
    for (int mi = 0; mi < 4; ++mi)
#pragma unroll
      for (int ni = 0; ni < 4; ++ni)
        acc[mi][ni] = __builtin_amdgcn_mfma_f32_16x16x32_bf16(af[mi], bfr[ni], acc[mi][ni], 0, 0, 0);
    __builtin_amdgcn_s_setprio(0);

    cur = (cur < 2) ? cur + 1 : 0;
  }

  float bcol[4];
  if (!ROW_BIAS) {
#pragma unroll
    for (int ni = 0; ni < 4; ++ni) bcol[ni] = bias[n0 + wc * 64 + ni * 16 + lr];
  }
#pragma unroll
  for (int mi = 0; mi < 4; ++mi) {
#pragma unroll
    for (int r = 0; r < 4; ++r) {
      int row = m0 + wr * 64 + mi * 16 + quad * 4 + r;
      float brow = ROW_BIAS ? bias[row] : 0.0f;
      size_t base = (size_t)row * ldY + n0 + wc * 64;
#pragma unroll
      for (int ni = 0; ni < 4; ++ni) {
        float y = acc[mi][ni][r] + (ROW_BIAS ? brow : bcol[ni]);
        int col = ni * 16 + lr;
        if (OUT_BF16) ((bf16_t*)Yv)[base + col] = (bf16_t)y;
        else          ((float*)Yv)[base + col]  = y;
      }
    }
  }
}

// ---- 256x256 8-phase GEMM for the QK projection (unchanged from R3) ----
#define QKK 2048
#define STAGE256(buf, ktoff) do {                                              \
  _Pragma("unroll") for (int i_ = 0; i_ < 4; ++i_)                             \
    async_copy16(gA + (ktoff) + (size_t)(i_ * 8) * QKK,                        \
                 &As[buf][(wv * 32 + i_ * 8) * 64]);                           \
  _Pragma("unroll") for (int i_ = 0; i_ < 4; ++i_)                             \
    async_copy16(gB + (ktoff) + (size_t)(i_ * 8) * QKK,                        \
                 &Bs[buf][(wv * 32 + i_ * 8) * 64]);                           \
} while (0)
#define DS_A256(mh) do {                                                       \
  _Pragma("unroll") for (int mi_ = 0; mi_ < 4; ++mi_)                          \
    _Pragma("unroll") for (int kk_ = 0; kk_ < 2; ++kk_)                        \
      af[mi_][kk_] = *(const bf16x8*)&As[p][(wr * 128 + ((mh)*4 + mi_) * 16 + lr) * 64 \
                                           + (((kk_ * 4 + quad) ^ (lr & 7)) * 8)];     \
} while (0)
#define DS_B256(nh) do {                                                       \
  _Pragma("unroll") for (int ni_ = 0; ni_ < 2; ++ni_)                          \
    _Pragma("unroll") for (int kk_ = 0; kk_ < 2; ++kk_)                        \
      bfq[ni_][kk_] = *(const bf16x8*)&Bs[p][(wc * 64 + ((nh)*2 + ni_) * 16 + lr) * 64 \
                                            + (((kk_ * 4 + quad) ^ (lr & 7)) * 8)];    \
} while (0)
#define MFMA_Q256(mh, nh) do {                                                 \
  __builtin_amdgcn_s_setprio(1);                                               \
  _Pragma("unroll") for (int mi_ = 0; mi_ < 4; ++mi_)                          \
    _Pragma("unroll") for (int ni_ = 0; ni_ < 2; ++ni_) {                      \
      acc[(mh)*4 + mi_][(nh)*2 + ni_] = __builtin_amdgcn_mfma_f32_16x16x32_bf16( \
          af[mi_][0], bfq[ni_][0], acc[(mh)*4 + mi_][(nh)*2 + ni_], 0, 0, 0);  \
      acc[(mh)*4 + mi_][(nh)*2 + ni_] = __builtin_amdgcn_mfma_f32_16x16x32_bf16( \
          af[mi_][1], bfq[ni_][1], acc[(mh)*4 + mi_][(nh)*2 + ni_], 0, 0, 0);  \
    }                                                                          \
  __builtin_amdgcn_s_setprio(0);                                               \
} while (0)

__global__ __launch_bounds__(512, 2)
void gemm256_bt(const bf16_t* __restrict__ A, const bf16_t* __restrict__ Bt,
                const float* __restrict__ bias, bf16_t* __restrict__ Y) {
  __shared__ __align__(16) bf16_t As[2][256 * 64];   // 2 x 32 KB
  __shared__ __align__(16) bf16_t Bs[2][256 * 64];   // 2 x 32 KB
  const int tid  = threadIdx.x;
  const int lane = tid & 63;
  const int wv   = tid >> 6;                 // 0..7
  const int wr   = wv >> 2, wc = wv & 3;     // 2 x 4 wave grid
  const int lr   = lane & 15, quad = lane >> 4;

  // bijective XCD swizzle: 256 WGs, 8 XCDs, 32 contiguous per XCD
  const int wg  = blockIdx.x;
  const int swz = (wg & 7) * 32 + (wg >> 3);
  const int m0  = (swz >> 4) * 256;          // 16 M-blocks
  const int n0  = (swz & 15) * 256;          // 16 N-blocks

  f32x4 acc[8][4] = {};

  // staging sources: lane l writes LDS chunk (l&7) of row-octet-sub (l>>3);
  // source chunk = (l&7) ^ (l>>3) so LDS chunk c of row r holds global
  // chunk c ^ (r&7)  (r&7 == l>>3 since row bases are multiples of 8)
  const int sub = lane >> 3;
  const int ch  = (lane & 7) ^ sub;
  const bf16_t* gA = A  + (size_t)(m0 + wv * 32 + sub) * QKK + ch * 8;
  const bf16_t* gB = Bt + (size_t)(n0 + wv * 32 + sub) * QKK + ch * 8;

  // prologue: tile 0 -> buf 0, drain, barrier
  STAGE256(0, 0);
  asm volatile("s_waitcnt vmcnt(0)" ::: "memory");
  __builtin_amdgcn_s_barrier();

  bf16x8 af[4][2], bfq[2][2];

  for (int t = 0; t < QKK / 64; ++t) {
    const int p   = t & 1;
    const int ktb = t * 64;

    // phase 0: burst-stage tile t+1 into buf^1; compute quadrant (mlo,nlo)
    if (t + 1 < QKK / 64) STAGE256(p ^ 1, ktb + 64);
    DS_A256(0); DS_B256(0);
    asm volatile("s_waitcnt lgkmcnt(0)" ::: "memory");
    __builtin_amdgcn_sched_barrier(0);
    MFMA_Q256(0, 0);
    __builtin_amdgcn_s_barrier();

    // phase 1: (mlo,nhi) -- A frags reused
    DS_B256(1);
    asm volatile("s_waitcnt lgkmcnt(0)" ::: "memory");
    __builtin_amdgcn_sched_barrier(0);
    MFMA_Q256(0, 1);
    __builtin_amdgcn_s_barrier();

    // phase 2: (mhi,nhi) -- B frags reused
    DS_A256(1);
    asm volatile("s_waitcnt lgkmcnt(0)" ::: "memory");
    __builtin_amdgcn_sched_barrier(0);
    MFMA_Q256(1, 1);
    __builtin_amdgcn_s_barrier();

    // phase 3: (mhi,nlo) -- A reused, B re-read; tile t+1 landed (counted:
    // issued ~3 phases ago). Barrier gates next group's reads + restaging.
    DS_B256(0);
    asm volatile("s_waitcnt vmcnt(0) lgkmcnt(0)" ::: "memory");
    __builtin_amdgcn_sched_barrier(0);
    MFMA_Q256(1, 0);
    __builtin_amdgcn_s_barrier();
  }

  // epilogue: + col bias, cast bf16, store
  float bcol[4];
#pragma unroll
  for (int ni = 0; ni < 4; ++ni) bcol[ni] = bias[n0 + wc * 64 + ni * 16 + lr];
#pragma unroll
  for (int fm = 0; fm < 8; ++fm) {
#pragma unroll
    for (int r = 0; r < 4; ++r) {
      size_t row  = (size_t)(m0 + wr * 128 + fm * 16 + quad * 4 + r);
      size_t base = row * 4096 + n0 + wc * 64;
#pragma unroll
      for (int ni = 0; ni < 4; ++ni)
        Y[base + ni * 16 + lr] = (bf16_t)(acc[fm][ni][r] + bcol[ni]);
    }
  }
}

// ---- Flash attention v7: software-pipelined KV loop (unchanged from R2) ----
#define BQ 128
#define BKV 64
#define LDQK 4096

__global__ __launch_bounds__(256, 2)
void attn_kernel(const bf16_t* __restrict__ QK, const bf16_t* __restrict__ Vt,
                 const float* __restrict__ mask, bf16_t* __restrict__ O) {
  __shared__ __align__(16) bf16_t Ks[2][BKV * 128];  // 2 x 16 KB, swizzle key row&15
  __shared__ __align__(16) bf16_t Vs[HDIM * BKV];    // 16 KB, swizzle key d&7
  __shared__ __align__(16) bf16_t Ps[BQ * BKV];      // 16 KB, swizzle key row&7
  __shared__ __align__(16) float  Msk[SEQ];          // 8 KB, pre-scaled by log2e

  const int tid  = threadIdx.x;
  const int lane = tid & 63;
  const int wv   = tid >> 6;                       // wave owns q rows [wv*32, wv*32+32)
  const int lr   = lane & 15, quad = lane >> 4;
  const int q0   = blockIdx.x * BQ;
  const int bh   = blockIdx.y;
  const int b    = bh >> 4, h = bh & 15;

  const bf16_t* Qg = QK + (size_t)(b * SEQ + q0) * LDQK + h * HDIM;
  const bf16_t* Kg = QK + (size_t)(b * SEQ) * LDQK + HIDDEN + h * HDIM;
  const bf16_t* Vg = Vt + (size_t)(h * HDIM) * MTOT + b * SEQ;
  const float*  mb = mask + b * SEQ;

  // Q fragments straight from global (one-time; L2/L3-served). 32 VGPRs.
  bf16x8 qf[2][4];
#pragma unroll
  for (int mi = 0; mi < 2; ++mi)
#pragma unroll
    for (int dk = 0; dk < 4; ++dk)
      qf[mi][dk] = *(const bf16x8*)(Qg + (size_t)(wv * 32 + mi * 16 + lr) * LDQK + dk * 32 + quad * 8);

  // mask -> LDS once, pre-scaled (keeps the main loop free of compiler VMEM)
  for (int i = tid; i < SEQ / 4; i += 256) {
    float4 mv = reinterpret_cast<const float4*>(mb)[i];
    Msk[i * 4 + 0] = mv.x * LOG2E;
    Msk[i * 4 + 1] = mv.y * LOG2E;
    Msk[i * 4 + 2] = mv.z * LOG2E;
    Msk[i * 4 + 3] = mv.w * LOG2E;
  }

  // staging: K tile 64x128 = 16 calls (4/wave); V tile 128x64 = 16 calls (4/wave)
  const int kcs = lane & 15;                       // K chunk (16B units)
  const int vcs = lane & 7;                        // V chunk
  const bf16_t* kgp[4]; const bf16_t* vgp[4];
  int lKo[4], lVo[4];
#pragma unroll
  for (int i = 0; i < 4; ++i) {
    int kr = wv * 16 + i * 4 + (lane >> 4);        // 0..63
    kgp[i] = Kg + (size_t)kr * LDQK + ((kcs ^ (kr & 15)) * 8);
    lKo[i] = (wv * 16 + i * 4) * 128;              // wave-uniform; HW adds lane*16B
    int vr = wv * 32 + i * 8 + (lane >> 3);        // 0..127
    vgp[i] = Vg + (size_t)vr * MTOT + ((vcs ^ (vr & 7)) * 8);
    lVo[i] = (wv * 32 + i * 8) * 64;
  }

  // drain Q/mask VMEM so in-loop vmcnt counts only staging ops
  asm volatile("s_waitcnt vmcnt(0)" ::: "memory");
#pragma unroll
  for (int i = 0; i < 4; ++i) async_copy16(kgp[i], &Ks[0][lKo[i]]);  // K(0) in flight
  asm volatile("s_waitcnt lgkmcnt(0)" ::: "memory");                 // Msk writes done
  __builtin_amdgcn_s_barrier();                                      // Msk visible

  float l_st[2][4] = {};
  f32x4 oacc[2][8] = {};

  for (int kt = 0; kt < SEQ; kt += BKV) {
    const int cur = (kt >> 6) & 1;
    const bf16_t* Kc = &Ks[cur][0];

    // all prior ds ops (incl. PV's Vs reads) retired before tiles are re-staged
    asm volatile("s_waitcnt lgkmcnt(0)" ::: "memory");
    __builtin_amdgcn_s_barrier();   // all waves done reading Vs/Ps/Ks[cur^1]
#pragma unroll
    for (int i = 0; i < 4; ++i) async_copy16(vgp[i] + kt, &Vs[lVo[i]]);
    if (kt + BKV < SEQ) {
#pragma unroll
      for (int i = 0; i < 4; ++i)
        async_copy16(kgp[i] + (size_t)(kt + BKV) * LDQK, &Ks[cur ^ 1][lKo[i]]);
      asm volatile("s_waitcnt vmcnt(8)" ::: "memory");  // K(kt) landed
    } else {
      asm volatile("s_waitcnt vmcnt(4)" ::: "memory");  // K(kt) landed
    }
    __builtin_amdgcn_s_barrier();   // K(kt) visible to all waves
    __builtin_amdgcn_sched_barrier(0);

    float mk[4];
#pragma unroll
    for (int ni = 0; ni < 4; ++ni) mk[ni] = Msk[kt + ni * 16 + lr];

    // S = Q K^T  (per wave: [32 q][64 k])
    f32x4 sacc[2][4] = {};
#pragma unroll
    for (int dk = 0; dk < 4; ++dk) {
      bf16x8 kf[4];
#pragma unroll
      for (int ni = 0; ni < 4; ++ni)
        kf[ni] = *(const bf16x8*)&Kc[(ni * 16 + lr) * 128 + (((dk * 4 + quad) ^ lr) * 8)];
#pragma unroll
      for (int mi = 0; mi < 2; ++mi)
#pragma unroll
        for (int ni = 0; ni < 4; ++ni)
          sacc[mi][ni] = __builtin_amdgcn_mfma_f32_16x16x32_bf16(qf[mi][dk], kf[ni], sacc[mi][ni], 0, 0, 0);
    }

    // unnormalized P = exp2(S*C1 + mask*log2e); C-layout row = quad*4+r, col = lr
#pragma unroll
    for (int mi = 0; mi < 2; ++mi) {
#pragma unroll
      for (int r = 0; r < 4; ++r) {
        float p0 = dev_exp2(fmaf(sacc[mi][0][r], C1EXP2, mk[0]));
        float p1 = dev_exp2(fmaf(sacc[mi][1][r], C1EXP2, mk[1]));
        float p2 = dev_exp2(fmaf(sacc[mi][2][r], C1EXP2, mk[2]));
        float p3 = dev_exp2(fmaf(sacc[mi][3][r], C1EXP2, mk[3]));
        int pr = wv * 32 + mi * 16 + quad * 4 + r;
        int key = pr & 7;
        Ps[pr * BKV + (((0 + (lr >> 3)) ^ key) * 8) + (lr & 7)] = (bf16_t)p0;
        Ps[pr * BKV + (((2 + (lr >> 3)) ^ key) * 8) + (lr & 7)] = (bf16_t)p1;
        Ps[pr * BKV + (((4 + (lr >> 3)) ^ key) * 8) + (lr & 7)] = (bf16_t)p2;
        Ps[pr * BKV + (((6 + (lr >> 3)) ^ key) * 8) + (lr & 7)] = (bf16_t)p3;
        l_st[mi][r] += (p0 + p1) + (p2 + p3);
      }
    }

    if (kt + BKV < SEQ) {
      asm volatile("s_waitcnt vmcnt(4)" ::: "memory");  // V(kt) landed, K(kt+1) in flight
    } else {
      asm volatile("s_waitcnt vmcnt(0)" ::: "memory");  // final drain
    }
    __builtin_amdgcn_s_barrier();   // V(kt) visible (Ps is wave-private)
    __builtin_amdgcn_sched_barrier(0);

    // O += P V   (per wave: [32 q][128 d])
#pragma unroll
    for (int ki = 0; ki < 2; ++ki) {
      bf16x8 pf[2];
#pragma unroll
      for (int mi = 0; mi < 2; ++mi)
        pf[mi] = *(const bf16x8*)&Ps[(wv * 32 + mi * 16 + lr) * BKV + (((ki * 4 + quad) ^ (lr & 7)) * 8)];
#pragma unroll
      for (int di = 0; di < 8; ++di) {
        bf16x8 vf = *(const bf16x8*)&Vs[(di * 16 + lr) * BKV + (((ki * 4 + quad) ^ (lr & 7)) * 8)];
#pragma unroll
        for (int mi = 0; mi < 2; ++mi)
          oacc[mi][di] = __builtin_amdgcn_mfma_f32_16x16x32_bf16(pf[mi], vf, oacc[mi][di], 0, 0, 0);
      }
    }
  }

  // epilogue: reduce l across the 16 lr-lanes, O /= l, write ctx bf16
  bf16_t* Ob = O + (size_t)(b * SEQ + q0) * HIDDEN + h * HDIM;
#pragma unroll
  for (int mi = 0; mi < 2; ++mi) {
#pragma unroll
    for (int r = 0; r < 4; ++r) {
      float s = l_st[mi][r];
      s += __shfl_xor(s, 1);
      s += __shfl_xor(s, 2);
      s += __shfl_xor(s, 4);
      s += __shfl_xor(s, 8);
      float inv = 1.0f / s;
      size_t rowoff = (size_t)(wv * 32 + mi * 16 + quad * 4 + r) * HIDDEN;
#pragma unroll
      for (int di = 0; di < 8; ++di)
        Ob[rowoff + di * 16 + lr] = (bf16_t)(oacc[mi][di][r] * inv);
    }
  }
}

extern "C" void kernel_launch(void* const* d_in, const int* in_sizes, int n_in,
                              void* d_out, int out_size, void* d_ws, size_t ws_size,
                              hipStream_t stream) {
  const float* x   = (const float*)d_in[0];
  const float* msk = (const float*)d_in[1];
  const float* Wq  = (const float*)d_in[2];
  const float* bq  = (const float*)d_in[3];
  const float* Wk  = (const float*)d_in[4];
  const float* bk  = (const float*)d_in[5];
  const float* Wv  = (const float*)d_in[6];
  const float* bv  = (const float*)d_in[7];
  const float* Wo  = (const float*)d_in[8];
  const float* bo  = (const float*)d_in[9];
  float* out = (float*)d_out;

  // workspace layout (bf16 elems), ~101 MB total
  bf16_t* Xb   = (bf16_t*)d_ws;
  bf16_t* Wqkb = Xb   + (size_t)MTOT * HIDDEN;            // Wq|Wk stacked [4096][2048]
  bf16_t* Wvb  = Wqkb + (size_t)2 * HIDDEN * HIDDEN;
  bf16_t* Wob  = Wvb  + (size_t)HIDDEN * HIDDEN;
  bf16_t* QKo  = Wob  + (size_t)HIDDEN * HIDDEN;          // [4096][4096]
  bf16_t* Vto  = QKo  + (size_t)MTOT * 2 * HIDDEN;        // [2048][4096]
  float*  bqk  = (float*)(Vto + (size_t)HIDDEN * MTOT);   // [4096] fp32
  bf16_t* Cb   = Xb;  // ctx aliases Xb (Xb dead after Vt GEMM)

  // fused casts: 6 regions x (HH/4 float4 / 256) blocks
  cvt_all<<<dim3(HIDDEN * HIDDEN / 4 / 256, 6), 256, 0, stream>>>(
      x, Wq, Wk, Wv, Wo, Xb, Wqkb, Wvb, Wob);
  pack_bias2<<<2 * HIDDEN / 256, 256, 0, stream>>>(bq, bk, bqk);

  // QK projection: [4096,2048] x [4096,2048]^T -> [4096][4096]  (8-phase 256^2)
  gemm256_bt<<<256, 512, 0, stream>>>(Xb, Wqkb, bqk, QKo);
  // V^T projection (operands swapped): [2048,2048] x [4096,2048]^T -> [2048][4096], row bias
  gemm_bt<true, true><<<dim3(32, 16), 256, 0, stream>>>(Wvb, Xb, bv, Vto,
                                                        HIDDEN, MTOT, HIDDEN, MTOT);
  // attention -> ctx bf16 [4096][2048]  (256-thread blocks, pipelined, 2 blocks/CU)
  attn_kernel<<<dim3(SEQ / BQ, BATCH * NHEADS), 256, 0, stream>>>(QKo, Vto, msk, Cb);
  // output projection -> fp32 out
  gemm_bt<false, false><<<dim3(16, 32), 256, 0, stream>>>(Cb, Wob, bo, out,
                                                          MTOT, HIDDEN, HIDDEN, HIDDEN);
}